// Round 11
// baseline (258.738 us; speedup 1.0000x reference)
//
#include <hip/hip_runtime.h>
#include <hip/hip_fp16.h>

typedef _Float16 f16;
typedef _Float16 f16x8 __attribute__((ext_vector_type(8)));
typedef float f32x4 __attribute__((ext_vector_type(4)));
typedef unsigned long long ull;

#define BB 4
#define TT 16
#define HH 64
#define WW 64
#define CC 32
#define FF 64
#define GG 256  // 4F gates

// counted-vmcnt wait; "memory" clobber blocks LDS/global ops from moving across it
#define WAITV(n) asm volatile("s_waitcnt vmcnt(" #n ")" ::: "memory")
// group barrier WITHOUT vmcnt drain: per-wave LDS-op drain + raw s_barrier, order-pinned
#define LGKBAR do { asm volatile("s_waitcnt lgkmcnt(0)" ::: "memory"); \
                    __builtin_amdgcn_s_barrier(); \
                    __builtin_amdgcn_sched_barrier(0); } while (0)

__device__ __forceinline__ float hsig(float z) {
    return fminf(fmaxf(0.2f * z + 0.5f, 0.f), 1.f);
}
__device__ __forceinline__ float tanh_fast(float x) {
    return 1.f - 2.f / (__expf(2.f * x) + 1.f);
}

__device__ __forceinline__ void async_copy16(const void* g, void* l) {
    __builtin_amdgcn_global_load_lds(
        (const __attribute__((address_space(1))) unsigned*)g,
        (__attribute__((address_space(3))) unsigned*)l, 16, 0, 0);
}

// --- Weight prep, piece-major (r4/r8/r9 proven): wcat[phase p][piece j][gate n][elem e] ---
// K-chunk c = p*3+cw starts at byte c*16384 (16 KB per chunk, linear).
__global__ void wprep_kernel(const float* __restrict__ wx, const float* __restrict__ wh,
                             f16* __restrict__ wcat) {
    int e = blockIdx.x * 256 + threadIdx.x;
    if (e < 9 * CC * GG) {                    // 73728: Wx, e = (tap*32+c)*256 + n
        int n = e & 255, k = e >> 8;
        int p = k / 96, r = k % 96;
        wcat[((p * 12 + (r >> 3)) * 256 + n) * 8 + (r & 7)] = (f16)wx[e];
    } else {
        e -= 9 * CC * GG;
        if (e < 9 * FF * GG) {                // 147456: Wh, e = (tap*64+f)*256 + n
            int n = e & 255, k = 288 + (e >> 8);
            int p = k / 96, r = k % 96;
            wcat[((p * 12 + (r >> 3)) * 256 + n) * 8 + (r & 7)] = (f16)wh[e];
        }
    }
}

// x staging with fused LayerNorm (r8 proven): 200 threads, 2/pixel, pair-shfl combine
__device__ __forceinline__ void stage_x(const float* __restrict__ x, int bb, int t,
                                        int ty, int tx, int tid,
                                        const float* sg, const float* sb,
                                        f16* __restrict__ xpatch) {
    if (tid < 200) {
        int pix = tid >> 1, part = tid & 1;
        int py = pix / 10, px_ = pix % 10;
        int gy = ty * 8 - 1 + py, gx = tx * 8 - 1 + px_;
        if (gy >= 0 && gy < HH && gx >= 0 && gx < WW) {
            const float* xp = x + ((size_t)(bb * TT + t) * (HH * WW)
                                   + gy * WW + gx) * CC + part * 16;
            float v[16];
            float s = 0.f, s2 = 0.f;
#pragma unroll
            for (int j = 0; j < 4; j++) {
                float4 t4 = *(const float4*)(xp + j * 4);
                v[j * 4] = t4.x; v[j * 4 + 1] = t4.y; v[j * 4 + 2] = t4.z; v[j * 4 + 3] = t4.w;
                s += t4.x + t4.y + t4.z + t4.w;
                s2 += t4.x * t4.x + t4.y * t4.y + t4.z * t4.z + t4.w * t4.w;
            }
            s += __shfl_xor(s, 1);            // pair (2k,2k+1) shares one pixel
            s2 += __shfl_xor(s2, 1);
            float mu = s * (1.f / CC);
            float var = s2 * (1.f / CC) - mu * mu;
            float rs = rsqrtf(var + 1e-3f);
            f16 o16[16];
#pragma unroll
            for (int c = 0; c < 16; c++)
                o16[c] = (f16)((v[c] - mu) * rs * sg[part * 16 + c] + sb[part * 16 + c]);
            f16x8* d = (f16x8*)&xpatch[pix * 72 + part * 16];
            d[0] = *(f16x8*)&o16[0];
            d[1] = *(f16x8*)&o16[8];
        }
    }
}

// ======== Fused: 16 ConvLSTM steps; formally-safe register fragment pipeline ========
// r9 structure (6 x 16KB chunk-buffers, group barriers) with:
//  - group-leading fragment read + cw=0/1 read-ahead (chunks all issued BEFORE the last
//    barrier — restores the issue-before-barrier invariant r10 broke);
//  - ONE WAITV(0) per group at the END (own next-group DMAs complete before the next
//    barrier => every read after a barrier is cross-wave race-free BY CONSTRUCTION;
//    latency hidden under the group's compute — m201 pattern). All per-chunk waits gone.
//  - next-step chunks 0-2 issued AFTER the epilogue __syncthreads (buffer-reuse safety),
//    covered by pool + stage_x, drained by a step-end WAITV(0).
__global__ __launch_bounds__(512, 2)
void fused_kernel(const float* __restrict__ x, const float* __restrict__ gamma,
                  const float* __restrict__ beta, const f16* __restrict__ wcat,
                  const float* __restrict__ bs, f16* __restrict__ halo,
                  float* __restrict__ out, unsigned* __restrict__ flags) {
    __shared__ __align__(16) f16 patches[3 * 7200];  // xpatch + hpatch[2], 43.2 KB
    __shared__ __align__(16) f16 wbuf[6 * 8192];     // 6 chunk-buffers x 16 KB = 96 KB
    __shared__ float sg[CC], sb[CC];

    f16* xpatch = patches;
    int tid = threadIdx.x;
    int tile = blockIdx.x;
    int bb = tile >> 6, ty = (tile >> 3) & 7, tx = tile & 7;
    int lane = tid & 63, w = tid >> 6;          // w in [0,8)
    int wm = w >> 2, nhalf = (w >> 1) & 1, wn = w & 1;
    int quad = lane >> 4, noff = lane & 15;

    if (tid < CC) sg[tid] = gamma[tid];
    else if (tid < 2 * CC) sb[tid - CC] = beta[tid - CC];

    // zero patch buffers once: out-of-image borders stay zero forever; h0 = 0
    for (int i = tid; i < 2700; i += 512)
        ((f16x8*)patches)[i] = (f16x8){0, 0, 0, 0, 0, 0, 0, 0};

    // per-lane weight base: wave w takes loads 2w, 2w+1 of each 16 KB chunk
    const char* gwb = (const char*)wcat + w * 2048 + lane * 16;

    int fch = (nhalf << 5) + (wn << 4) + noff;  // f-channel in [0,64)
    float b_i = bs[fch], b_f = bs[64 + fch], b_c = bs[128 + fch], b_o = bs[192 + fch];

    float creg[2][4];
#pragma unroll
    for (int mt = 0; mt < 2; mt++)
#pragma unroll
        for (int r = 0; r < 4; r++) creg[mt][r] = 0.f;

    // per-thread A-read pixel bases (constant across steps)
    int mrow[2];
#pragma unroll
    for (int mt = 0; mt < 2; mt++) {
        int m = (wm << 5) + (mt << 4) + noff;
        mrow[mt] = ((m >> 3) * 10 + (m & 7)) * 72 + (quad << 3);
    }
    // B-read gate-row offsets (f16 units within a chunk's quad-piece)
    int rB[4];
#pragma unroll
    for (int cls = 0; cls < 4; cls++) rB[cls] = ((cls << 6) + fch) << 3;

    __syncthreads();  // patch zeroing + sg/sb visible

    // initial staging: x[0] + weight chunks 0-2; one-time drain so the first group's
    // reads (after the top LGKBAR) see complete chunk data from ALL waves
    stage_x(x, bb, 0, ty, tx, tid, sg, sb, xpatch);
#pragma unroll
    for (int k = 0; k < 3; k++) {
        async_copy16(gwb + (size_t)k * 16384, &wbuf[k * 8192 + w * 1024]);
        async_copy16(gwb + (size_t)k * 16384 + 1024, &wbuf[k * 8192 + w * 1024 + 512]);
    }
    WAITV(0);

    for (int t = 0; t < TT; t++) {
        f16* hp_cur = patches + 7200 + (t & 1) * 7200;
        f16* hp_nxt = patches + 7200 + ((t + 1) & 1) * 7200;

        LGKBAR;  // xpatch/hpatch ds_writes visible; chunk 0-2 data already complete

        f32x4 acc[2][4];
#pragma unroll
        for (int i = 0; i < 2; i++)
#pragma unroll
            for (int j = 0; j < 4; j++) acc[i][j] = (f32x4){0.f, 0.f, 0.f, 0.f};

        f16x8 fA[2][2], fB[2][4];   // fragment double-buffer (parity = chunk&1)

        // fragment read for chunk cn (compile-time under unroll); data guaranteed in LDS
        auto READF = [&](int cn) {
            const int pn = cn & 1;
            const bool isx = cn < 9;
            const int hc = cn - 9;
            const int tap = isx ? cn : (hc >> 1);
            const int coff = isx ? 0 : ((hc & 1) << 5);
            const f16* ap = isx ? xpatch : hp_cur;
            const int toff = ((tap / 3) * 10 + (tap % 3)) * 72 + coff;
            fA[pn][0] = *(const f16x8*)&ap[mrow[0] + toff];
            fA[pn][1] = *(const f16x8*)&ap[mrow[1] + toff];
            const f16* wbc = &wbuf[(cn % 6) * 8192 + quad * 2048];
#pragma unroll
            for (int cls = 0; cls < 4; cls++)
                fB[pn][cls] = *(const f16x8*)&wbc[rB[cls]];
        };
        auto MFMA8 = [&](int pc) {
            __builtin_amdgcn_s_setprio(1);
#pragma unroll
            for (int cls = 0; cls < 4; cls++) {
                acc[0][cls] = __builtin_amdgcn_mfma_f32_16x16x32_f16(fA[pc][0], fB[pc][cls], acc[0][cls], 0, 0, 0);
                acc[1][cls] = __builtin_amdgcn_mfma_f32_16x16x32_f16(fA[pc][1], fB[pc][cls], acc[1][cls], 0, 0, 0);
            }
            __builtin_amdgcn_s_setprio(0);
        };

        // ---- 9 groups of 3 K-chunks ----
#pragma unroll
        for (int g = 0; g < 9; ++g) {
            if (g > 0) LGKBAR;   // group-g chunk data complete in ALL waves (end-of-group wait)
            READF(3 * g);        // leading read; overlapped only with halo/prefetch issue
            // halo staged in group 2; first h read is group 3's leading read (chunk 9),
            // after the group-3 LGKBAR which drains these ds_writes
            if (g == 2 && t > 0 && tid >= 256 && tid < 400) {
                int e = tid - 256;                // [0,144): 36 ring px x 4 quarters of 16ch
                int hx = e >> 2, quarter = e & 3;
                int py, px_;
                if (hx < 10)      { py = 0; px_ = hx; }
                else if (hx < 20) { py = 9; px_ = hx - 10; }
                else if (hx < 28) { py = 1 + (hx - 20); px_ = 0; }
                else              { py = 1 + (hx - 28); px_ = 9; }
                int gy = ty * 8 - 1 + py, gx = tx * 8 - 1 + px_;
                if (gy >= 0 && gy < HH && gx >= 0 && gx < WW) {
                    int nb = bb * 64 + ((gy >> 3) << 3) + (gx >> 3);
                    while (__hip_atomic_load(&flags[nb], __ATOMIC_RELAXED,
                                             __HIP_MEMORY_SCOPE_AGENT) < (unsigned)t)
                        __builtin_amdgcn_s_sleep(1);
                    const ull* src = (const ull*)(halo + ((size_t)(t * BB + bb) * (HH * WW)
                                                         + gy * WW + gx) * FF) + quarter * 4;
                    f16* dst = &hp_cur[(py * 10 + px_) * 72 + quarter * 16];
#pragma unroll
                    for (int j = 0; j < 4; j++) {
                        ull vv = __hip_atomic_load(src + j, __ATOMIC_RELAXED,
                                                   __HIP_MEMORY_SCOPE_AGENT);
                        *(ull*)(dst + j * 4) = vv;
                    }
                }
            }
            if (g < 8) {  // prefetch group g+1 (chunks 3g+3..3g+5)
#pragma unroll
                for (int k = 0; k < 3; k++) {
                    int c = 3 * g + 3 + k;
                    async_copy16(gwb + (size_t)c * 16384,
                                 &wbuf[(c % 6) * 8192 + w * 1024]);
                    async_copy16(gwb + (size_t)c * 16384 + 1024,
                                 &wbuf[(c % 6) * 8192 + w * 1024 + 512]);
                }
            }
#pragma unroll
            for (int cw = 0; cw < 3; ++cw) {
                const int c = 3 * g + cw;
                if (cw < 2) READF(c + 1);   // within-group read-ahead (issued pre-barrier)
                MFMA8(c & 1);
            }
            if (g < 8) WAITV(0);  // own g+1 DMAs done (cover = this group's compute)
        }

        // ---- epilogue: gates + state; h -> LDS (next patch) + ring -> global ----
#pragma unroll
        for (int mt = 0; mt < 2; mt++) {
#pragma unroll
            for (int r = 0; r < 4; r++) {
                int m = (wm << 5) + (mt << 4) + (quad << 2) + r;  // C/D row = quad*4+reg
                int py8 = m >> 3, px8 = m & 7;
                float zi = acc[mt][0][r] + b_i;
                float zf = acc[mt][1][r] + b_f;
                float zc = acc[mt][2][r] + b_c;
                float zo = acc[mt][3][r] + b_o;
                float ig = hsig(zi), fg = hsig(zf), og = hsig(zo);
                float cn = fg * creg[mt][r] + ig * tanh_fast(zc);
                creg[mt][r] = cn;
                f16 hval = (f16)(og * tanh_fast(cn));
                hp_nxt[((py8 + 1) * 10 + px8 + 1) * 72 + fch] = hval;
                if (py8 == 0 || py8 == 7 || px8 == 0 || px8 == 7) {
                    union { f16 f; unsigned short u; } cvt; cvt.f = hval;
                    unsigned short* hp = (unsigned short*)halo
                        + ((size_t)((t + 1) * BB + bb) * (HH * WW)
                           + (ty * 8 + py8) * WW + (tx * 8 + px8)) * FF + fch;
                    __hip_atomic_store(hp, cvt.u, __ATOMIC_RELAXED, __HIP_MEMORY_SCOPE_AGENT);
                }
            }
        }
        __syncthreads();  // full drain: hp_nxt visible + ring stores at coherent point
        if (tid == 0)
            __hip_atomic_store(&flags[tile], (unsigned)(t + 1), __ATOMIC_RELAXED,
                               __HIP_MEMORY_SCOPE_AGENT);

        // ---- pool 2x2 from hp_nxt -> out (interior px only; disjoint from halo ring) ----
        {
            int o = tid * 2;
            int f0 = o & 63;
            int ox2 = (o >> 6) & 3, oy2 = (o >> 8) & 3;
            int row = 1 + oy2 * 2, col = 1 + ox2 * 2;
            const f16* hb = &hp_nxt[(row * 10 + col) * 72 + f0];
            float v0 = fmaxf(fmaxf((float)hb[0], (float)hb[72]),
                             fmaxf((float)hb[720], (float)hb[792]));
            float v1 = fmaxf(fmaxf((float)hb[1], (float)hb[73]),
                             fmaxf((float)hb[721], (float)hb[793]));
            size_t ofs = (((size_t)(bb * TT + t) * 32 + (ty * 4 + oy2)) * 32
                          + (tx * 4 + ox2)) * 64 + f0;
            float2 v2; v2.x = v0; v2.y = v1;
            *(float2*)(out + ofs) = v2;
        }

        // ---- next-step staging (AFTER the epilogue barrier: buffers 0-2 reuse-safe
        // cross-wave). Issue DMAs first, cover their latency with stage_x, then drain so
        // the next top LGKBAR implies chunk 0-2 completeness in all waves. ----
        if (t + 1 < TT) {
#pragma unroll
            for (int k = 0; k < 3; k++) {
                async_copy16(gwb + (size_t)k * 16384, &wbuf[k * 8192 + w * 1024]);
                async_copy16(gwb + (size_t)k * 16384 + 1024, &wbuf[k * 8192 + w * 1024 + 512]);
            }
            stage_x(x, bb, t + 1, ty, tx, tid, sg, sb, xpatch);
            WAITV(0);
        }
    }
}

extern "C" void kernel_launch(void* const* d_in, const int* in_sizes, int n_in,
                              void* d_out, int out_size, void* d_ws, size_t ws_size,
                              hipStream_t stream) {
    const float* x = (const float*)d_in[0];
    const float* gamma = (const float*)d_in[1];
    const float* beta = (const float*)d_in[2];
    const float* wx = (const float*)d_in[3];
    const float* wh = (const float*)d_in[4];
    const float* bs = (const float*)d_in[5];
    float* out = (float*)d_out;

    // workspace layout (all 16B-aligned)
    char* ws = (char*)d_ws;
    f16* wcat = (f16*)(ws + 16777216);        //    442,368 B (piece-major layout)
    unsigned* flags = (unsigned*)(ws + 17219584);  // 256 x 4 B
    f16* hs = (f16*)(ws + 21413888);          // 35,651,584 B (halo exchange buffer)

    hipMemsetAsync(flags, 0, 256 * 4, stream);
    wprep_kernel<<<864, 256, 0, stream>>>(wx, wh, wcat);

    // Regular launch: 256 blocks x 512 threads x 139.6 KB LDS = exactly 1 block/CU by
    // capacity -> all blocks resident at dispatch; the flags protocol needs nothing more.
    fused_kernel<<<256, 512, 0, stream>>>(x, gamma, beta, wcat, bs, hs, out, flags);
}